// Round 10
// baseline (121.554 us; speedup 1.0000x reference)
//
#include <hip/hip_runtime.h>
#include <hip/hip_fp16.h>
#include <math.h>

// GATv2Conv forward. fp16 xl/xr; CSR via hierarchical LDS binning.
// Proj: MFMA f16 GEMM (single K-pass). Aggregate: 32 thr/node, packed-fp16
// front-end (vector pk ops + abs-trick leaky + fdot2 + fma_mix), unroll x4.

#define NN 50000
#define NE 800000
#define NHEADS 8
#define CH 16
#define FDIM 128
#define NEG_SLOPE 0.2f

#define BSHIFT 8
#define NBUCK ((NN + 255) >> 8)          // 196
#define CHUNK 4096
#define NCHUNK ((NE + CHUNK - 1) / CHUNK) // 196
#define CNT_CHUNK 1024
#define NCHUNK_CNT ((NE + CNT_CHUNK - 1) / CNT_CHUNK) // 782

typedef _Float16 half8 __attribute__((ext_vector_type(8)));
typedef _Float16 h2v  __attribute__((ext_vector_type(2)));
typedef float f32x4 __attribute__((ext_vector_type(4)));

// ---------------- projection GEMM via MFMA -------------------------------
#define PBM 64
#define PTILES ((NN + PBM - 1) / PBM)   // 782

__global__ __launch_bounds__(256) void gat_proj_mfma(
        const float* __restrict__ x,
        const float* __restrict__ Wl,
        const float* __restrict__ Wr,
        __half* __restrict__ xl,
        __half* __restrict__ xr) {
    __shared__ __half Al[PBM][FDIM];   // 16 KB, 16B-chunk XOR-swizzled
    __shared__ __half Bl[PBM][FDIM];   // 16 KB

    const int t    = threadIdx.x;
    const int lane = t & 63;
    const int wave = t >> 6;
    const int wm   = wave >> 1;
    const int wn   = wave & 1;
    const int lr   = lane & 15;
    const int lh   = lane >> 4;

    const int row0 = blockIdx.x * PBM;
    const int y    = blockIdx.y;               // 0..3
    const float* __restrict__ Wp = (y < 2) ? Wl : Wr;
    __half* __restrict__ outp    = (y < 2) ? xl : xr;
    const int wrow0   = (y & 1) * 64;
    const int colbase = wrow0;

    #pragma unroll
    for (int i = 0; i < 4; ++i) {
        int c   = t + i * 256;
        int row = c >> 4;
        int c16 = c & 15;
        int sc  = c16 ^ (row & 7);
        {
            int arow = row0 + row;
            if (arow >= NN) arow = NN - 1;
            const float4* src = reinterpret_cast<const float4*>(
                x + (size_t)arow * FDIM + c16 * 8);
            float4 v0 = src[0];
            float4 v1 = src[1];
            union { uint4 u; __half2 h[4]; } pk;
            pk.h[0] = __floats2half2_rn(v0.x, v0.y);
            pk.h[1] = __floats2half2_rn(v0.z, v0.w);
            pk.h[2] = __floats2half2_rn(v1.x, v1.y);
            pk.h[3] = __floats2half2_rn(v1.z, v1.w);
            *reinterpret_cast<uint4*>(&Al[row][sc * 8]) = pk.u;
        }
        {
            const float4* src = reinterpret_cast<const float4*>(
                Wp + (size_t)(wrow0 + row) * FDIM + c16 * 8);
            float4 v0 = src[0];
            float4 v1 = src[1];
            union { uint4 u; __half2 h[4]; } pk;
            pk.h[0] = __floats2half2_rn(v0.x, v0.y);
            pk.h[1] = __floats2half2_rn(v0.z, v0.w);
            pk.h[2] = __floats2half2_rn(v1.x, v1.y);
            pk.h[3] = __floats2half2_rn(v1.z, v1.w);
            *reinterpret_cast<uint4*>(&Bl[row][sc * 8]) = pk.u;
        }
    }
    __syncthreads();

    f32x4 acc[2][2] = {};
    const char* Ab = reinterpret_cast<const char*>(&Al[0][0]);
    const char* Bb = reinterpret_cast<const char*>(&Bl[0][0]);

    #pragma unroll
    for (int kc = 0; kc < 4; ++kc) {
        half8 a[2], b[2];
        #pragma unroll
        for (int mi = 0; mi < 2; ++mi) {
            int row = wm * 32 + mi * 16 + lr;
            int bc  = (kc * 64 + 16 * lh) ^ ((row & 7) << 4);
            a[mi] = *reinterpret_cast<const half8*>(Ab + row * 256 + bc);
        }
        #pragma unroll
        for (int ni = 0; ni < 2; ++ni) {
            int row = wn * 32 + ni * 16 + lr;
            int bc  = (kc * 64 + 16 * lh) ^ ((row & 7) << 4);
            b[ni] = *reinterpret_cast<const half8*>(Bb + row * 256 + bc);
        }
        #pragma unroll
        for (int mi = 0; mi < 2; ++mi)
            #pragma unroll
            for (int ni = 0; ni < 2; ++ni)
                acc[mi][ni] = __builtin_amdgcn_mfma_f32_16x16x32_f16(
                    a[mi], b[ni], acc[mi][ni], 0, 0, 0);
    }

    #pragma unroll
    for (int mi = 0; mi < 2; ++mi) {
        #pragma unroll
        for (int ni = 0; ni < 2; ++ni) {
            int gcol = colbase + wn * 32 + ni * 16 + lr;
            #pragma unroll
            for (int r = 0; r < 4; ++r) {
                int grow = row0 + wm * 32 + mi * 16 + 4 * lh + r;
                if (grow < NN)
                    outp[(size_t)grow * FDIM + gcol] = __float2half(acc[mi][ni][r]);
            }
        }
    }
}

// ---------------- CSR build via hierarchical binning ---------------------
__global__ void gat_zero_cnt(int* __restrict__ bcnt) {
    int t = threadIdx.x;
    if (t < NBUCK) bcnt[t] = 0;
}

__global__ __launch_bounds__(256) void gat_bucket_count(
        const int* __restrict__ ei, int* __restrict__ bcnt) {
    __shared__ int hist[NBUCK];
    int t = threadIdx.x;
    for (int i = t; i < NBUCK; i += 256) hist[i] = 0;
    __syncthreads();
    int base = blockIdx.x * CNT_CHUNK;
    #pragma unroll
    for (int i = 0; i < CNT_CHUNK / 256; ++i) {
        int m = base + i * 256 + t;
        if (m < NE) atomicAdd(&hist[ei[NE + m] >> BSHIFT], 1);
    }
    __syncthreads();
    for (int i = t; i < NBUCK; i += 256)
        if (hist[i]) atomicAdd(&bcnt[i], hist[i]);
}

__global__ __launch_bounds__(256) void gat_bucket_scan(
        const int* __restrict__ bcnt,
        int* __restrict__ bbase,
        int* __restrict__ bcursor,
        int* __restrict__ rowstart) {
    __shared__ int buf[256];
    int t = threadIdx.x;
    int v = (t < NBUCK) ? bcnt[t] : 0;
    buf[t] = v;
    __syncthreads();
    for (int off = 1; off < 256; off <<= 1) {
        int add = (t >= off) ? buf[t - off] : 0;
        __syncthreads();
        buf[t] += add;
        __syncthreads();
    }
    if (t < NBUCK) {
        int excl = buf[t] - v;
        bbase[t]   = excl;
        bcursor[t] = excl;
    }
    if (t == 0) {
        bbase[NBUCK] = NE;
        rowstart[NN] = NE;
    }
}

__global__ __launch_bounds__(256) void gat_bin_pass(
        const int* __restrict__ ei,
        int* __restrict__ bcursor,
        int2* __restrict__ binned) {
    __shared__ int hist[NBUCK];
    __shared__ int base_l[NBUCK];
    int t = threadIdx.x;
    for (int i = t; i < NBUCK; i += 256) hist[i] = 0;
    __syncthreads();

    int cbase = blockIdx.x * CHUNK;
    int s[CHUNK / 256], d[CHUNK / 256], r[CHUNK / 256];
    #pragma unroll
    for (int i = 0; i < CHUNK / 256; ++i) {
        int m = cbase + i * 256 + t;
        if (m < NE) {
            s[i] = ei[m];
            d[i] = ei[NE + m];
            r[i] = atomicAdd(&hist[d[i] >> BSHIFT], 1);
        } else {
            d[i] = -1;
        }
    }
    __syncthreads();
    for (int i = t; i < NBUCK; i += 256)
        base_l[i] = hist[i] ? atomicAdd(&bcursor[i], hist[i]) : 0;
    __syncthreads();
    #pragma unroll
    for (int i = 0; i < CHUNK / 256; ++i) {
        if (d[i] >= 0) {
            int pos = base_l[d[i] >> BSHIFT] + r[i];
            binned[pos] = make_int2(s[i], d[i] & 255);
        }
    }
}

__global__ __launch_bounds__(256) void gat_fine_pass(
        const int2* __restrict__ binned,
        const int* __restrict__ bbase,
        int* __restrict__ rowstart,
        int* __restrict__ csr_src) {
    __shared__ int cnt_c[256];
    __shared__ int sbuf[256];
    __shared__ int cur_c[256];
    int t = threadIdx.x;
    int b = blockIdx.x;
    int base = bbase[b];
    int cnt  = bbase[b + 1] - base;

    cnt_c[t] = 0;
    __syncthreads();
    for (int j = t; j < cnt; j += 256)
        atomicAdd(&cnt_c[binned[base + j].y], 1);
    __syncthreads();

    int v = cnt_c[t];
    sbuf[t] = v;
    __syncthreads();
    for (int off = 1; off < 256; off <<= 1) {
        int add = (t >= off) ? sbuf[t - off] : 0;
        __syncthreads();
        sbuf[t] += add;
        __syncthreads();
    }
    int excl = sbuf[t] - v;
    cur_c[t] = excl;
    int node = (b << BSHIFT) + t;
    if (node < NN) rowstart[node] = base + excl;
    __syncthreads();

    for (int j = t; j < cnt; j += 256) {
        int2 e = binned[base + j];
        int pos = atomicAdd(&cur_c[e.y], 1);
        csr_src[base + pos] = e.x;
    }
}

// ---------------- fused aggregate (packed fp16 front-end) ----------------
// leaky(s) = 0.6*s + 0.4*|s|  (exact for slope 0.2);  |s| = bits & 0x7FFF7FFF
__device__ __forceinline__ float gat_dot4_h(h2v e01, h2v e23,
                                            h2v at01, h2v at23) {
#if __has_builtin(__builtin_amdgcn_fdot2)
    float p = __builtin_amdgcn_fdot2(e01, at01, 0.0f, false);
    return __builtin_amdgcn_fdot2(e23, at23, p, false);
#else
    return (float)e01[0] * (float)at01[0] + (float)e01[1] * (float)at01[1]
         + (float)e23[0] * (float)at23[0] + (float)e23[1] * (float)at23[1];
#endif
}

__device__ __forceinline__ void gat_edge_step_h(
        const h2v xi01, const h2v xi23,
        const h2v at01, const h2v at23,
        uint2 raw, float4& acc, float& den) {
    union uh { unsigned u; h2v v; };
    uh j01, j23;
    j01.u = raw.x; j23.u = raw.y;
    h2v s01 = xi01 + j01.v;
    h2v s23 = xi23 + j23.v;
    uh b01, b23, a01, a23;
    b01.v = s01; b23.v = s23;
    a01.u = b01.u & 0x7FFF7FFFu;
    a23.u = b23.u & 0x7FFF7FFFu;
    const h2v c1 = {(_Float16)0.6f, (_Float16)0.6f};
    const h2v c2 = {(_Float16)0.4f, (_Float16)0.4f};
    h2v e01 = s01 * c1 + a01.v * c2;
    h2v e23 = s23 * c1 + a23.v * c2;
    float p = gat_dot4_h(e01, e23, at01, at23);
    p += __shfl_xor(p, 1);
    p += __shfl_xor(p, 2);
    float ea = __expf(p);
    // fpext(f16)*f32 + f32 -> v_fma_mix_f32
    acc.x = fmaf((float)j01.v[0], ea, acc.x);
    acc.y = fmaf((float)j01.v[1], ea, acc.y);
    acc.z = fmaf((float)j23.v[0], ea, acc.z);
    acc.w = fmaf((float)j23.v[1], ea, acc.w);
    den += ea;
}

__global__ __launch_bounds__(256) void gat_aggregate_kernel(
        const __half* __restrict__ xl,
        const __half* __restrict__ xr,
        const float* __restrict__ att,
        const float* __restrict__ bias,
        const int* __restrict__ rowstart,
        const int* __restrict__ csr_src,
        float* __restrict__ out) {
    int node = blockIdx.x * 8 + (threadIdx.x >> 5);
    int u = threadIdx.x & 31;
    if (node >= NN) return;

    union { uint2 r; struct { unsigned a, b; } w; } xiraw;
    xiraw.r = *reinterpret_cast<const uint2*>(xr + (size_t)node * FDIM + u * 4);
    union uh { unsigned u; h2v v; };
    uh xi0, xi1;
    xi0.u = xiraw.w.a; xi1.u = xiraw.w.b;
    const float4 atf = *reinterpret_cast<const float4*>(att + u * 4);
    h2v a01 = {(_Float16)atf.x, (_Float16)atf.y};
    h2v a23 = {(_Float16)atf.z, (_Float16)atf.w};
    const float4 bi = *reinterpret_cast<const float4*>(bias + u * 4);
    int e0 = rowstart[node];
    int e1 = rowstart[node + 1];

    float4 acc0 = {0,0,0,0}, acc1 = {0,0,0,0}, acc2 = {0,0,0,0}, acc3 = {0,0,0,0};
    float den0 = 0.0f, den1 = 0.0f, den2 = 0.0f, den3 = 0.0f;

    int e = e0;
    for (; e + 4 <= e1; e += 4) {
        int s0 = csr_src[e + 0];
        int s1 = csr_src[e + 1];
        int s2 = csr_src[e + 2];
        int s3 = csr_src[e + 3];
        uint2 r0 = *reinterpret_cast<const uint2*>(xl + (size_t)s0 * FDIM + u * 4);
        uint2 r1 = *reinterpret_cast<const uint2*>(xl + (size_t)s1 * FDIM + u * 4);
        uint2 r2 = *reinterpret_cast<const uint2*>(xl + (size_t)s2 * FDIM + u * 4);
        uint2 r3 = *reinterpret_cast<const uint2*>(xl + (size_t)s3 * FDIM + u * 4);
        gat_edge_step_h(xi0.v, xi1.v, a01, a23, r0, acc0, den0);
        gat_edge_step_h(xi0.v, xi1.v, a01, a23, r1, acc1, den1);
        gat_edge_step_h(xi0.v, xi1.v, a01, a23, r2, acc2, den2);
        gat_edge_step_h(xi0.v, xi1.v, a01, a23, r3, acc3, den3);
    }
    for (; e < e1; ++e) {
        int s0 = csr_src[e];
        uint2 r0 = *reinterpret_cast<const uint2*>(xl + (size_t)s0 * FDIM + u * 4);
        gat_edge_step_h(xi0.v, xi1.v, a01, a23, r0, acc0, den0);
    }

    float4 acc;
    acc.x = (acc0.x + acc1.x) + (acc2.x + acc3.x);
    acc.y = (acc0.y + acc1.y) + (acc2.y + acc3.y);
    acc.z = (acc0.z + acc1.z) + (acc2.z + acc3.z);
    acc.w = (acc0.w + acc1.w) + (acc2.w + acc3.w);
    float den = (den0 + den1) + (den2 + den3);

    float inv = 1.0f / (den + 1e-16f);
    float4 o;
    o.x = acc.x * inv + bi.x;
    o.y = acc.y * inv + bi.y;
    o.z = acc.z * inv + bi.z;
    o.w = acc.w * inv + bi.w;
    *reinterpret_cast<float4*>(out + (size_t)node * FDIM + u * 4) = o;
}

extern "C" void kernel_launch(void* const* d_in, const int* in_sizes, int n_in,
                              void* d_out, int out_size, void* d_ws, size_t ws_size,
                              hipStream_t stream) {
    const float* x    = (const float*)d_in[0];
    const int*   ei   = (const int*)d_in[1];
    const float* Wl   = (const float*)d_in[2];
    const float* Wr   = (const float*)d_in[3];
    const float* att  = (const float*)d_in[4];
    const float* bias = (const float*)d_in[5];
    float* out = (float*)d_out;

    __half* xl = (__half*)d_ws;                      // NN*FDIM fp16
    __half* xr = xl + (size_t)NN * FDIM;             // NN*FDIM fp16
    int2* binned   = (int2*)(xr + (size_t)NN * FDIM);// NE int2
    int* csr_src   = (int*)(binned + NE);            // NE
    int* rowstart  = csr_src + NE;                   // NN+1 (pad)
    int* bcnt      = rowstart + NN + 8;              // NBUCK (pad 256)
    int* bbase     = bcnt + 256;                     // NBUCK+1 (pad 256)
    int* bcursor   = bbase + 256;                    // NBUCK

    gat_zero_cnt<<<1, 256, 0, stream>>>(bcnt);
    gat_bucket_count<<<NCHUNK_CNT, 256, 0, stream>>>(ei, bcnt);
    gat_bucket_scan<<<1, 256, 0, stream>>>(bcnt, bbase, bcursor, rowstart);
    gat_bin_pass<<<NCHUNK, 256, 0, stream>>>(ei, bcursor, binned);
    gat_fine_pass<<<NBUCK, 256, 0, stream>>>(binned, bbase, rowstart, csr_src);

    dim3 pgrid(PTILES, 4);
    gat_proj_mfma<<<pgrid, 256, 0, stream>>>(x, Wl, Wr, xl, xr);

    gat_aggregate_kernel<<<(NN + 7) / 8, 256, 0, stream>>>(
        xl, xr, att, bias, rowstart, csr_src, out);
}

// Round 11
// 87.274 us; speedup vs baseline: 1.3928x; 1.3928x over previous
//
#include <hip/hip_runtime.h>
#include <hip/hip_fp16.h>
#include <math.h>

// GATv2Conv forward. fp16 xl/xr; padded-bucket CSR (no count/scan passes);
// merged MFMA proj (x staged once, Wl+Wr together); packed-fp16 aggregate.

#define NN 50000
#define NE 800000
#define NHEADS 8
#define CH 16
#define FDIM 128
#define NEG_SLOPE 0.2f

#define BSHIFT 8
#define NBUCK ((NN + 255) >> 8)           // 196 coarse buckets (dst>>8)
#define BCAP 5120                          // mean 4082, sigma 64 -> 16 sigma
#define CHUNK 4096
#define NCHUNK ((NE + CHUNK - 1) / CHUNK)  // 196

typedef _Float16 half8 __attribute__((ext_vector_type(8)));
typedef _Float16 h2v  __attribute__((ext_vector_type(2)));
typedef float f32x4 __attribute__((ext_vector_type(4)));

// ---------------- projection GEMM via MFMA (merged Wl+Wr) ----------------
// Block: 64 x-rows x 256 outputs (xl 0..127, xr 128..255). 512 thr, 8 waves.
#define PBM 64
#define PTILES ((NN + PBM - 1) / PBM)   // 782

__global__ __launch_bounds__(512) void gat_proj_mfma(
        const float* __restrict__ x,
        const float* __restrict__ Wl,
        const float* __restrict__ Wr,
        __half* __restrict__ xl,
        __half* __restrict__ xr) {
    __shared__ __half Al[PBM][FDIM];    // 16 KB, 16B-chunk XOR-swizzled
    __shared__ __half Bl[256][FDIM];    // 64 KB, rows 0..127 Wl, 128..255 Wr

    const int t    = threadIdx.x;
    const int lane = t & 63;
    const int wave = t >> 6;            // 0..7
    const int wm   = wave >> 2;         // 0..1  (32-row half of A)
    const int wn   = wave & 3;          // 0..3  (64-col quarter of B)
    const int lr   = lane & 15;
    const int lh   = lane >> 4;

    const int row0 = blockIdx.x * PBM;

    // ---- stage A (64 rows), 2 chunks/thread ----
    #pragma unroll
    for (int i = 0; i < 2; ++i) {
        int c   = t + i * 512;          // 0..1023
        int row = c >> 4;
        int c16 = c & 15;
        int sc  = c16 ^ (row & 7);
        int arow = row0 + row;
        if (arow >= NN) arow = NN - 1;
        const float4* src = reinterpret_cast<const float4*>(
            x + (size_t)arow * FDIM + c16 * 8);
        float4 v0 = src[0];
        float4 v1 = src[1];
        union { uint4 u; __half2 h[4]; } pk;
        pk.h[0] = __floats2half2_rn(v0.x, v0.y);
        pk.h[1] = __floats2half2_rn(v0.z, v0.w);
        pk.h[2] = __floats2half2_rn(v1.x, v1.y);
        pk.h[3] = __floats2half2_rn(v1.z, v1.w);
        *reinterpret_cast<uint4*>(&Al[row][sc * 8]) = pk.u;
    }
    // ---- stage B (256 W-rows), 8 chunks/thread ----
    #pragma unroll
    for (int i = 0; i < 8; ++i) {
        int c   = t + i * 512;          // 0..4095
        int row = c >> 4;               // 0..255
        int c16 = c & 15;
        int sc  = c16 ^ (row & 7);
        const float* wr = (row < 128) ? (Wl + (size_t)row * FDIM)
                                      : (Wr + (size_t)(row - 128) * FDIM);
        const float4* src = reinterpret_cast<const float4*>(wr + c16 * 8);
        float4 v0 = src[0];
        float4 v1 = src[1];
        union { uint4 u; __half2 h[4]; } pk;
        pk.h[0] = __floats2half2_rn(v0.x, v0.y);
        pk.h[1] = __floats2half2_rn(v0.z, v0.w);
        pk.h[2] = __floats2half2_rn(v1.x, v1.y);
        pk.h[3] = __floats2half2_rn(v1.z, v1.w);
        *reinterpret_cast<uint4*>(&Bl[row][sc * 8]) = pk.u;
    }
    __syncthreads();

    f32x4 acc[2][4] = {};
    const char* Ab = reinterpret_cast<const char*>(&Al[0][0]);
    const char* Bb = reinterpret_cast<const char*>(&Bl[0][0]);

    #pragma unroll
    for (int kc = 0; kc < 4; ++kc) {
        half8 a[2], b[4];
        #pragma unroll
        for (int mi = 0; mi < 2; ++mi) {
            int row = wm * 32 + mi * 16 + lr;
            int bc  = (kc * 64 + 16 * lh) ^ ((row & 7) << 4);
            a[mi] = *reinterpret_cast<const half8*>(Ab + row * 256 + bc);
        }
        #pragma unroll
        for (int ni = 0; ni < 4; ++ni) {
            int row = wn * 64 + ni * 16 + lr;
            int bc  = (kc * 64 + 16 * lh) ^ ((row & 7) << 4);
            b[ni] = *reinterpret_cast<const half8*>(Bb + row * 256 + bc);
        }
        #pragma unroll
        for (int mi = 0; mi < 2; ++mi)
            #pragma unroll
            for (int ni = 0; ni < 4; ++ni)
                acc[mi][ni] = __builtin_amdgcn_mfma_f32_16x16x32_f16(
                    a[mi], b[ni], acc[mi][ni], 0, 0, 0);
    }

    // ---- epilogue: col=lane&15 within frag, row=4*(lane>>4)+reg ----
    #pragma unroll
    for (int mi = 0; mi < 2; ++mi) {
        #pragma unroll
        for (int ni = 0; ni < 4; ++ni) {
            int gc = wn * 64 + ni * 16 + lr;          // 0..255
            __half* outp = (gc < 128) ? xl : xr;
            int col = gc & 127;
            #pragma unroll
            for (int r = 0; r < 4; ++r) {
                int grow = row0 + wm * 32 + mi * 16 + 4 * lh + r;
                if (grow < NN)
                    outp[(size_t)grow * FDIM + col] = __float2half(acc[mi][ni][r]);
            }
        }
    }
}

// ---------------- CSR build: padded buckets ------------------------------
__global__ void gat_init_cursor(int* __restrict__ bcursor) {
    int t = threadIdx.x;
    if (t < NBUCK) bcursor[t] = t * BCAP;
}

// bin edges into padded coarse buckets; packed (src, dst&255)
__global__ __launch_bounds__(256) void gat_bin_pass(
        const int* __restrict__ ei,
        int* __restrict__ bcursor,
        int2* __restrict__ binned) {
    __shared__ int hist[NBUCK];
    __shared__ int base_l[NBUCK];
    int t = threadIdx.x;
    for (int i = t; i < NBUCK; i += 256) hist[i] = 0;
    __syncthreads();

    int cbase = blockIdx.x * CHUNK;
    int s[CHUNK / 256], d[CHUNK / 256], r[CHUNK / 256];
    #pragma unroll
    for (int i = 0; i < CHUNK / 256; ++i) {
        int m = cbase + i * 256 + t;
        if (m < NE) {
            s[i] = ei[m];
            d[i] = ei[NE + m];
            r[i] = atomicAdd(&hist[d[i] >> BSHIFT], 1);
        } else {
            d[i] = -1;
        }
    }
    __syncthreads();
    for (int i = t; i < NBUCK; i += 256)
        base_l[i] = hist[i] ? atomicAdd(&bcursor[i], hist[i]) : 0;
    __syncthreads();
    #pragma unroll
    for (int i = 0; i < CHUNK / 256; ++i) {
        if (d[i] >= 0) {
            int pos = base_l[d[i] >> BSHIFT] + r[i];
            binned[pos] = make_int2(s[i], d[i] & 255);
        }
    }
}

// per-bucket fine sort: rowstart/rowend + csr_src within padded region
__global__ __launch_bounds__(256) void gat_fine_pass(
        const int2* __restrict__ binned,
        const int* __restrict__ bcursor,
        int* __restrict__ rowstart,
        int* __restrict__ rowend,
        int* __restrict__ csr_src) {
    __shared__ int cnt_c[256];
    __shared__ int sbuf[256];
    __shared__ int cur_c[256];
    int t = threadIdx.x;
    int b = blockIdx.x;
    int base = b * BCAP;
    int cnt  = bcursor[b] - base;

    cnt_c[t] = 0;
    __syncthreads();
    for (int j = t; j < cnt; j += 256)
        atomicAdd(&cnt_c[binned[base + j].y], 1);
    __syncthreads();

    int v = cnt_c[t];
    sbuf[t] = v;
    __syncthreads();
    for (int off = 1; off < 256; off <<= 1) {
        int add = (t >= off) ? sbuf[t - off] : 0;
        __syncthreads();
        sbuf[t] += add;
        __syncthreads();
    }
    int excl = sbuf[t] - v;
    cur_c[t] = excl;
    int node = (b << BSHIFT) + t;
    if (node < NN) {
        rowstart[node] = base + excl;
        rowend[node]   = base + excl + v;
    }
    __syncthreads();

    for (int j = t; j < cnt; j += 256) {
        int2 e = binned[base + j];
        int pos = atomicAdd(&cur_c[e.y], 1);
        csr_src[base + pos] = e.x;
    }
}

// ---------------- fused aggregate (packed fp16 front-end) ----------------
// leaky(s) = 0.6*s + 0.4*|s|  (exact for slope 0.2)
__device__ __forceinline__ float gat_dot4_h(h2v e01, h2v e23,
                                            h2v at01, h2v at23) {
#if __has_builtin(__builtin_amdgcn_fdot2)
    float p = __builtin_amdgcn_fdot2(e01, at01, 0.0f, false);
    return __builtin_amdgcn_fdot2(e23, at23, p, false);
#else
    return (float)e01[0] * (float)at01[0] + (float)e01[1] * (float)at01[1]
         + (float)e23[0] * (float)at23[0] + (float)e23[1] * (float)at23[1];
#endif
}

__device__ __forceinline__ void gat_edge_step_h(
        const h2v xi01, const h2v xi23,
        const h2v at01, const h2v at23,
        uint2 raw, float4& acc, float& den) {
    union uh { unsigned u; h2v v; };
    uh j01, j23;
    j01.u = raw.x; j23.u = raw.y;
    h2v s01 = xi01 + j01.v;
    h2v s23 = xi23 + j23.v;
    uh b01, b23, a01, a23;
    b01.v = s01; b23.v = s23;
    a01.u = b01.u & 0x7FFF7FFFu;
    a23.u = b23.u & 0x7FFF7FFFu;
    const h2v c1 = {(_Float16)0.6f, (_Float16)0.6f};
    const h2v c2 = {(_Float16)0.4f, (_Float16)0.4f};
    h2v e01 = s01 * c1 + a01.v * c2;
    h2v e23 = s23 * c1 + a23.v * c2;
    float p = gat_dot4_h(e01, e23, at01, at23);
    p += __shfl_xor(p, 1);
    p += __shfl_xor(p, 2);
    float ea = __expf(p);
    acc.x = fmaf((float)j01.v[0], ea, acc.x);
    acc.y = fmaf((float)j01.v[1], ea, acc.y);
    acc.z = fmaf((float)j23.v[0], ea, acc.z);
    acc.w = fmaf((float)j23.v[1], ea, acc.w);
    den += ea;
}

__global__ __launch_bounds__(256) void gat_aggregate_kernel(
        const __half* __restrict__ xl,
        const __half* __restrict__ xr,
        const float* __restrict__ att,
        const float* __restrict__ bias,
        const int* __restrict__ rowstart,
        const int* __restrict__ rowend,
        const int* __restrict__ csr_src,
        float* __restrict__ out) {
    int node = blockIdx.x * 8 + (threadIdx.x >> 5);
    int u = threadIdx.x & 31;
    if (node >= NN) return;

    union { uint2 r; struct { unsigned a, b; } w; } xiraw;
    xiraw.r = *reinterpret_cast<const uint2*>(xr + (size_t)node * FDIM + u * 4);
    union uh { unsigned u; h2v v; };
    uh xi0, xi1;
    xi0.u = xiraw.w.a; xi1.u = xiraw.w.b;
    const float4 atf = *reinterpret_cast<const float4*>(att + u * 4);
    h2v a01 = {(_Float16)atf.x, (_Float16)atf.y};
    h2v a23 = {(_Float16)atf.z, (_Float16)atf.w};
    const float4 bi = *reinterpret_cast<const float4*>(bias + u * 4);
    int e0 = rowstart[node];
    int e1 = rowend[node];

    float4 acc0 = {0,0,0,0}, acc1 = {0,0,0,0}, acc2 = {0,0,0,0}, acc3 = {0,0,0,0};
    float den0 = 0.0f, den1 = 0.0f, den2 = 0.0f, den3 = 0.0f;

    int e = e0;
    for (; e + 4 <= e1; e += 4) {
        int s0 = csr_src[e + 0];
        int s1 = csr_src[e + 1];
        int s2 = csr_src[e + 2];
        int s3 = csr_src[e + 3];
        uint2 r0 = *reinterpret_cast<const uint2*>(xl + (size_t)s0 * FDIM + u * 4);
        uint2 r1 = *reinterpret_cast<const uint2*>(xl + (size_t)s1 * FDIM + u * 4);
        uint2 r2 = *reinterpret_cast<const uint2*>(xl + (size_t)s2 * FDIM + u * 4);
        uint2 r3 = *reinterpret_cast<const uint2*>(xl + (size_t)s3 * FDIM + u * 4);
        gat_edge_step_h(xi0.v, xi1.v, a01, a23, r0, acc0, den0);
        gat_edge_step_h(xi0.v, xi1.v, a01, a23, r1, acc1, den1);
        gat_edge_step_h(xi0.v, xi1.v, a01, a23, r2, acc2, den2);
        gat_edge_step_h(xi0.v, xi1.v, a01, a23, r3, acc3, den3);
    }
    for (; e < e1; ++e) {
        int s0 = csr_src[e];
        uint2 r0 = *reinterpret_cast<const uint2*>(xl + (size_t)s0 * FDIM + u * 4);
        gat_edge_step_h(xi0.v, xi1.v, a01, a23, r0, acc0, den0);
    }

    float4 acc;
    acc.x = (acc0.x + acc1.x) + (acc2.x + acc3.x);
    acc.y = (acc0.y + acc1.y) + (acc2.y + acc3.y);
    acc.z = (acc0.z + acc1.z) + (acc2.z + acc3.z);
    acc.w = (acc0.w + acc1.w) + (acc2.w + acc3.w);
    float den = (den0 + den1) + (den2 + den3);

    float inv = 1.0f / (den + 1e-16f);
    float4 o;
    o.x = acc.x * inv + bi.x;
    o.y = acc.y * inv + bi.y;
    o.z = acc.z * inv + bi.z;
    o.w = acc.w * inv + bi.w;
    *reinterpret_cast<float4*>(out + (size_t)node * FDIM + u * 4) = o;
}

extern "C" void kernel_launch(void* const* d_in, const int* in_sizes, int n_in,
                              void* d_out, int out_size, void* d_ws, size_t ws_size,
                              hipStream_t stream) {
    const float* x    = (const float*)d_in[0];
    const int*   ei   = (const int*)d_in[1];
    const float* Wl   = (const float*)d_in[2];
    const float* Wr   = (const float*)d_in[3];
    const float* att  = (const float*)d_in[4];
    const float* bias = (const float*)d_in[5];
    float* out = (float*)d_out;

    // ws layout (d_ws 256-aligned)
    __half* xl = (__half*)d_ws;                       // NN*FDIM fp16 (12.8 MB)
    __half* xr = xl + (size_t)NN * FDIM;              // 12.8 MB
    int2* binned   = (int2*)(xr + (size_t)NN * FDIM); // NBUCK*BCAP int2 (8.0 MB)
    int* csr_src   = (int*)(binned + (size_t)NBUCK * BCAP); // 4.0 MB
    int* rowstart  = csr_src + (size_t)NBUCK * BCAP;  // NN
    int* rowend    = rowstart + NN + 8;               // NN
    int* bcursor   = rowend + NN + 8;                 // NBUCK

    gat_init_cursor<<<1, 256, 0, stream>>>(bcursor);
    gat_bin_pass<<<NCHUNK, 256, 0, stream>>>(ei, bcursor, binned);
    gat_fine_pass<<<NBUCK, 256, 0, stream>>>(binned, bcursor, rowstart, rowend, csr_src);

    gat_proj_mfma<<<PTILES, 512, 0, stream>>>(x, Wl, Wr, xl, xr);

    gat_aggregate_kernel<<<(NN + 7) / 8, 256, 0, stream>>>(
        xl, xr, att, bias, rowstart, rowend, csr_src, out);
}